// Round 4
// baseline (188.992 us; speedup 1.0000x reference)
//
#include <hip/hip_runtime.h>
#include <hip/hip_bf16.h>

#define NS 32           // nsample (fixed by setup_inputs)
#define WPB 4           // waves per block (block = 256 threads)

// One wave (64 lanes) per query point:
//   Phase 1: chunked scan over the query's batch points, ballot-append the
//            first NS in-radius point indices (ascending order == reference's
//            top_k(-key) semantics) into per-wave LDS. Early exit when full.
//   Phase 2: gather xyz/features for the NS slots and write the grouped
//            output + idx (as float).
__global__ __launch_bounds__(256) void qgp_kernel(
    const float* __restrict__ xyz,        // (Ntot, 3)
    const int*   __restrict__ xyz_cnt,    // (B,)
    const float* __restrict__ nxyz,       // (Mtot, 3)
    const float* __restrict__ nr,         // (Mtot,)
    const int*   __restrict__ nxyz_cnt,   // (B,)
    const float* __restrict__ feat,       // (Ntot, C)
    float* __restrict__ out_feat,         // (Mtot, 3+C, NS)
    float* __restrict__ out_idx,          // (Mtot, NS) as float
    int B, int Mtot, int C)
{
    __shared__ int idx_buf[WPB][NS];

    const int wv   = threadIdx.x >> 6;
    const int lane = threadIdx.x & 63;
    const int q    = blockIdx.x * WPB + wv;
    if (q >= Mtot) return;

    // ---- locate batch for this query (B is tiny; L2-hot scalar loads) ----
    int b = 0, xoff = 0, npts = 0;
    {
        int acc = 0;
        for (int i = 0; i < B; ++i) {
            int c = nxyz_cnt[i];
            if (q >= acc) b = i;          // last batch whose start <= q
            acc += c;
        }
        for (int i = 0; i < b; ++i) xoff += xyz_cnt[i];
        npts = xyz_cnt[b];
    }
    const float* xb = xyz + (size_t)xoff * 3;

    const float qx = nxyz[(size_t)q * 3 + 0];
    const float qy = nxyz[(size_t)q * 3 + 1];
    const float qz = nxyz[(size_t)q * 3 + 2];
    const float r  = nr[q];
    const float r2 = __fmul_rn(r, r);

    const unsigned long long lane_mask = (1ull << lane) - 1ull;

    // ---- Phase 1: ordered ball-query scan ----
    int cnt = 0;
    for (int base = 0; base < npts && cnt < NS; base += 64 * 4) {
#pragma unroll
        for (int u = 0; u < 4; ++u) {
            const int k = base + u * 64 + lane;
            bool ok = false;
            if (k < npts) {
                // match XLA exactly: sub, mul, left-assoc add, NO fma contraction
                const float dx = __fsub_rn(qx, xb[(size_t)k * 3 + 0]);
                const float dy = __fsub_rn(qy, xb[(size_t)k * 3 + 1]);
                const float dz = __fsub_rn(qz, xb[(size_t)k * 3 + 2]);
                const float d2 = __fadd_rn(__fadd_rn(__fmul_rn(dx, dx),
                                                     __fmul_rn(dy, dy)),
                                           __fmul_rn(dz, dz));
                ok = d2 < r2;
            }
            const unsigned long long m = __ballot(ok);
            if (ok) {
                const int pos = cnt + __popcll(m & lane_mask);
                if (pos < NS) idx_buf[wv][pos] = k;
            }
            cnt += __popcll(m);
        }
    }
    __builtin_amdgcn_wave_barrier();   // keep LDS writes ordered before reads

    // ---- Phase 2: gather + write ----
    const bool empty = (cnt == 0);
    const int cnt32  = cnt < NS ? cnt : NS;
    const int s = lane & 31;           // sample slot
    const int h = lane >> 5;           // feature half (0: c<32, 1: c>=32)

    int sidx = 0;
    if (!empty) sidx = idx_buf[wv][(s < cnt32) ? s : 0];

    const size_t ob = (size_t)q * (size_t)(3 + C) * NS;

    if (h == 0) {
        out_idx[(size_t)q * NS + s] = (float)sidx;
        float px = 0.f, py = 0.f, pz = 0.f;
        if (!empty) {
            px = __fsub_rn(xb[(size_t)sidx * 3 + 0], qx);
            py = __fsub_rn(xb[(size_t)sidx * 3 + 1], qy);
            pz = __fsub_rn(xb[(size_t)sidx * 3 + 2], qz);
        }
        out_feat[ob + 0 * NS + s] = px;
        out_feat[ob + 1 * NS + s] = py;
        out_feat[ob + 2 * NS + s] = pz;
    }

    const float* frow = feat + (size_t)(xoff + sidx) * C;
    if (C == 64) {
        const float4* frow4 = reinterpret_cast<const float4*>(frow);
#pragma unroll
        for (int j = 0; j < 8; ++j) {
            float4 f;
            if (empty) { f.x = f.y = f.z = f.w = 0.f; }
            else       { f = frow4[h * 8 + j]; }
            const int cb = 3 + h * 32 + j * 4;
            out_feat[ob + (size_t)(cb + 0) * NS + s] = f.x;
            out_feat[ob + (size_t)(cb + 1) * NS + s] = f.y;
            out_feat[ob + (size_t)(cb + 2) * NS + s] = f.z;
            out_feat[ob + (size_t)(cb + 3) * NS + s] = f.w;
        }
    } else {
        for (int c = h; c < C; c += 2) {
            out_feat[ob + (size_t)(3 + c) * NS + s] = empty ? 0.f : frow[c];
        }
    }
}

extern "C" void kernel_launch(void* const* d_in, const int* in_sizes, int n_in,
                              void* d_out, int out_size, void* d_ws, size_t ws_size,
                              hipStream_t stream) {
    const float* xyz      = (const float*)d_in[0];
    const int*   xyz_cnt  = (const int*)d_in[1];
    const float* nxyz     = (const float*)d_in[2];
    const float* nr       = (const float*)d_in[3];
    const int*   nxyz_cnt = (const int*)d_in[4];
    const float* feat     = (const float*)d_in[5];

    const int B    = in_sizes[1];
    const int Ntot = in_sizes[0] / 3;
    const int Mtot = in_sizes[2] / 3;
    const int C    = in_sizes[5] / Ntot;

    float* out_feat = (float*)d_out;
    float* out_idx  = out_feat + (size_t)Mtot * (size_t)(3 + C) * NS;

    const int blocks = (Mtot + WPB - 1) / WPB;
    qgp_kernel<<<blocks, 256, 0, stream>>>(xyz, xyz_cnt, nxyz, nr, nxyz_cnt,
                                           feat, out_feat, out_idx,
                                           B, Mtot, C);
}

// Round 5
// 152.168 us; speedup vs baseline: 1.2420x; 1.2420x over previous
//
#include <hip/hip_runtime.h>
#include <hip/hip_bf16.h>

#define NS 32           // nsample (fixed by setup_inputs)
#define WPB 4           // waves per block (block = 256 threads)

__device__ __forceinline__ int mbcnt64(unsigned long long m) {
    // popcount of mask bits strictly below this lane
    int c = __builtin_amdgcn_mbcnt_lo((unsigned)(m & 0xffffffffull), 0u);
    return __builtin_amdgcn_mbcnt_hi((unsigned)(m >> 32), c);
}

__device__ __forceinline__ float dist2_xla(float qx, float qy, float qz,
                                           float x, float y, float z) {
    // match XLA exactly: sub, mul, left-assoc add, NO fma contraction
    const float dx = __fsub_rn(qx, x);
    const float dy = __fsub_rn(qy, y);
    const float dz = __fsub_rn(qz, z);
    return __fadd_rn(__fadd_rn(__fmul_rn(dx, dx), __fmul_rn(dy, dy)),
                     __fmul_rn(dz, dz));
}

// One wave (64 lanes) per query point.
// Phase 1: scan in groups of 256 points; each lane owns 4 consecutive points
//          loaded via 3 contiguous float4 (48B/lane, coalesced 3KB/group).
//          Ordered append (ascending point index == reference top_k(-key))
//          via 4 sub-ballots + mbcnt prefix. Next group's loads are issued
//          before current group's ballot to hide L2 latency. Early exit when
//          NS found.
// Phase 2: gather xyz/features for the NS slots and write grouped output+idx.
__global__ __launch_bounds__(256) void qgp_kernel(
    const float* __restrict__ xyz,        // (Ntot, 3)
    const int*   __restrict__ xyz_cnt,    // (B,)
    const float* __restrict__ nxyz,       // (Mtot, 3)
    const float* __restrict__ nr,         // (Mtot,)
    const int*   __restrict__ nxyz_cnt,   // (B,)
    const float* __restrict__ feat,       // (Ntot, C)
    float* __restrict__ out_feat,         // (Mtot, 3+C, NS)
    float* __restrict__ out_idx,          // (Mtot, NS) as float
    int B, int Mtot, int C)
{
    __shared__ int idx_buf[WPB][NS];

    const int wv   = threadIdx.x >> 6;
    const int lane = threadIdx.x & 63;
    const int q    = blockIdx.x * WPB + wv;
    if (q >= Mtot) return;

    // ---- locate batch for this query ----
    int b = 0, xoff = 0, npts = 0;
    {
        int acc = 0;
        for (int i = 0; i < B; ++i) {
            int c = nxyz_cnt[i];
            if (q >= acc) b = i;
            acc += c;
        }
        for (int i = 0; i < b; ++i) xoff += xyz_cnt[i];
        npts = xyz_cnt[b];
    }
    const float* xb = xyz + (size_t)xoff * 3;

    const float qx = nxyz[(size_t)q * 3 + 0];
    const float qy = nxyz[(size_t)q * 3 + 1];
    const float qz = nxyz[(size_t)q * 3 + 2];
    const float r  = nr[q];
    const float r2 = __fmul_rn(r, r);

    const unsigned long long lane_mask = (1ull << lane) - 1ull;

    int cnt = 0;

    // ---- Phase 1 main: groups of 256 points, 3x float4 per lane ----
    const int ngroups = npts >> 8;             // full groups of 256
    if (ngroups > 0) {
        const float4* xb4 = reinterpret_cast<const float4*>(xb);
        int g = 0;
        // prime group 0
        float4 A = xb4[(size_t)lane * 3 + 0];
        float4 Bv = xb4[(size_t)lane * 3 + 1];
        float4 Cv = xb4[(size_t)lane * 3 + 2];
        for (;;) {
            const bool has_next = (g + 1 < ngroups);
            float4 An, Bn, Cn;
            if (has_next) {
                const size_t nb = (size_t)(g + 1) * 192 + (size_t)lane * 3;
                An = xb4[nb + 0];
                Bn = xb4[nb + 1];
                Cn = xb4[nb + 2];
            }
            // points: p0=(A.x,A.y,A.z) p1=(A.w,B.x,B.y) p2=(B.z,B.w,C.x) p3=(C.y,C.z,C.w)
            const bool ok0 = dist2_xla(qx, qy, qz, A.x,  A.y,  A.z)  < r2;
            const bool ok1 = dist2_xla(qx, qy, qz, A.w,  Bv.x, Bv.y) < r2;
            const bool ok2 = dist2_xla(qx, qy, qz, Bv.z, Bv.w, Cv.x) < r2;
            const bool ok3 = dist2_xla(qx, qy, qz, Cv.y, Cv.z, Cv.w) < r2;

            const unsigned long long m0 = __ballot(ok0);
            const unsigned long long m1 = __ballot(ok1);
            const unsigned long long m2 = __ballot(ok2);
            const unsigned long long m3 = __ballot(ok3);

            // lexicographic (lane-major, sub-minor) ordered positions
            const int excl = mbcnt64(m0) + mbcnt64(m1) + mbcnt64(m2) + mbcnt64(m3);
            const int tot  = __popcll(m0) + __popcll(m1) + __popcll(m2) + __popcll(m3);

            const int kbase = g * 256 + lane * 4;
            int p = cnt + excl;
            if (ok0) { if (p < NS) idx_buf[wv][p] = kbase + 0; ++p; }
            if (ok1) { if (p < NS) idx_buf[wv][p] = kbase + 1; ++p; }
            if (ok2) { if (p < NS) idx_buf[wv][p] = kbase + 2; ++p; }
            if (ok3) { if (p < NS) idx_buf[wv][p] = kbase + 3; ++p; }
            cnt += tot;                         // wave-uniform

            if (cnt >= NS || !has_next) break;
            A = An; Bv = Bn; Cv = Cn; ++g;
        }
    }

    // ---- Phase 1 tail: leftover points (npts % 256), 64 at a time ----
    for (int base = ngroups << 8; base < npts && cnt < NS; base += 64) {
        const int k = base + lane;
        bool ok = false;
        if (k < npts) {
            ok = dist2_xla(qx, qy, qz,
                           xb[(size_t)k * 3 + 0],
                           xb[(size_t)k * 3 + 1],
                           xb[(size_t)k * 3 + 2]) < r2;
        }
        const unsigned long long m = __ballot(ok);
        if (ok) {
            const int pos = cnt + __popcll(m & lane_mask);
            if (pos < NS) idx_buf[wv][pos] = k;
        }
        cnt += __popcll(m);
    }
    __builtin_amdgcn_wave_barrier();   // keep LDS writes ordered before reads

    // ---- Phase 2: gather + write ----
    const bool empty = (cnt == 0);
    const int cnt32  = cnt < NS ? cnt : NS;
    const int s = lane & 31;           // sample slot
    const int h = lane >> 5;           // feature half (0: c<32, 1: c>=32)

    int sidx = 0;
    if (!empty) sidx = idx_buf[wv][(s < cnt32) ? s : 0];

    const size_t ob = (size_t)q * (size_t)(3 + C) * NS;

    if (h == 0) {
        out_idx[(size_t)q * NS + s] = (float)sidx;
        float px = 0.f, py = 0.f, pz = 0.f;
        if (!empty) {
            px = __fsub_rn(xb[(size_t)sidx * 3 + 0], qx);
            py = __fsub_rn(xb[(size_t)sidx * 3 + 1], qy);
            pz = __fsub_rn(xb[(size_t)sidx * 3 + 2], qz);
        }
        out_feat[ob + 0 * NS + s] = px;
        out_feat[ob + 1 * NS + s] = py;
        out_feat[ob + 2 * NS + s] = pz;
    }

    const float* frow = feat + (size_t)(xoff + sidx) * C;
    if (C == 64) {
        const float4* frow4 = reinterpret_cast<const float4*>(frow);
#pragma unroll
        for (int j = 0; j < 8; ++j) {
            float4 f;
            if (empty) { f.x = f.y = f.z = f.w = 0.f; }
            else       { f = frow4[h * 8 + j]; }
            const int cb = 3 + h * 32 + j * 4;
            out_feat[ob + (size_t)(cb + 0) * NS + s] = f.x;
            out_feat[ob + (size_t)(cb + 1) * NS + s] = f.y;
            out_feat[ob + (size_t)(cb + 2) * NS + s] = f.z;
            out_feat[ob + (size_t)(cb + 3) * NS + s] = f.w;
        }
    } else {
        for (int c = h; c < C; c += 2) {
            out_feat[ob + (size_t)(3 + c) * NS + s] = empty ? 0.f : frow[c];
        }
    }
}

extern "C" void kernel_launch(void* const* d_in, const int* in_sizes, int n_in,
                              void* d_out, int out_size, void* d_ws, size_t ws_size,
                              hipStream_t stream) {
    const float* xyz      = (const float*)d_in[0];
    const int*   xyz_cnt  = (const int*)d_in[1];
    const float* nxyz     = (const float*)d_in[2];
    const float* nr       = (const float*)d_in[3];
    const int*   nxyz_cnt = (const int*)d_in[4];
    const float* feat     = (const float*)d_in[5];

    const int B    = in_sizes[1];
    const int Ntot = in_sizes[0] / 3;
    const int Mtot = in_sizes[2] / 3;
    const int C    = in_sizes[5] / Ntot;

    float* out_feat = (float*)d_out;
    float* out_idx  = out_feat + (size_t)Mtot * (size_t)(3 + C) * NS;

    const int blocks = (Mtot + WPB - 1) / WPB;
    qgp_kernel<<<blocks, 256, 0, stream>>>(xyz, xyz_cnt, nxyz, nr, nxyz_cnt,
                                           feat, out_feat, out_idx,
                                           B, Mtot, C);
}

// Round 7
// 135.276 us; speedup vs baseline: 1.3971x; 1.1249x over previous
//
#include <hip/hip_runtime.h>
#include <hip/hip_bf16.h>

#define NS   32          // nsample (fixed by setup_inputs)
#define WPB  4           // waves per block (block = 256 threads)
#define GD   10          // grid cells per axis; CELL = 1.0 over [0,10]^3 box
#define GD3  (GD*GD*GD)
#define CAP  256         // per-wave candidate capacity (expected max ~110)
#define IMAX 0x7fffffff

__device__ __forceinline__ int clampi(int v, int lo, int hi) {
    return v < lo ? lo : (v > hi ? hi : v);
}

__device__ __forceinline__ int cell_of(float x, float y, float z) {
    const int cx = clampi((int)floorf(x), 0, GD - 1);
    const int cy = clampi((int)floorf(y), 0, GD - 1);
    const int cz = clampi((int)floorf(z), 0, GD - 1);
    return (cz * GD + cy) * GD + cx;   // x fastest -> x-rows contiguous
}

__device__ __forceinline__ float dist2_xla(float qx, float qy, float qz,
                                           float x, float y, float z) {
    // match XLA exactly: sub, mul, left-assoc add, NO fma contraction
    const float dx = __fsub_rn(qx, x);
    const float dy = __fsub_rn(qy, y);
    const float dz = __fsub_rn(qz, z);
    return __fadd_rn(__fadd_rn(__fmul_rn(dx, dx), __fmul_rn(dy, dy)),
                     __fmul_rn(dz, dz));
}

__device__ __forceinline__ void find_batch(const int* cnts, int B, int p,
                                           int* b_out, int* off_out) {
    int b = 0, off = 0, acc = 0;
    for (int i = 0; i < B; ++i) {
        int c = cnts[i];
        if (p >= acc) { b = i; off = acc; }
        acc += c;
    }
    *b_out = b; *off_out = off;
}

// ---------------- grid build ----------------

__global__ void count_kernel(const float* __restrict__ xyz,
                             const int* __restrict__ xyz_cnt,
                             int* __restrict__ cnt, int B, int Ntot) {
    const int p = blockIdx.x * blockDim.x + threadIdx.x;
    if (p >= Ntot) return;
    int b, boff; find_batch(xyz_cnt, B, p, &b, &boff);
    const float x = xyz[(size_t)p * 3 + 0];
    const float y = xyz[(size_t)p * 3 + 1];
    const float z = xyz[(size_t)p * 3 + 2];
    atomicAdd(&cnt[b * GD3 + cell_of(x, y, z)], 1);
}

// single block; requires ncells+1 <= 2048
__global__ __launch_bounds__(1024) void prefix_kernel(int* __restrict__ cursor,     // in: counts, out: excl prefix
                                                      int* __restrict__ cell_start, // out: (ncells+1)
                                                      int ncells) {
    __shared__ int s[2048];
    const int t = threadIdx.x;
    for (int i = t; i < 2048; i += 1024) s[i] = (i < ncells) ? cursor[i] : 0;
    __syncthreads();
    for (int off = 1; off < 2048; off <<= 1) {
        const int v0 = s[t];
        const int a0 = (t >= off) ? s[t - off] : 0;
        const int v1 = s[t + 1024];
        const int a1 = s[t + 1024 - off];
        __syncthreads();
        s[t] = v0 + a0;
        s[t + 1024] = v1 + a1;
        __syncthreads();
    }
    for (int i = t; i < ncells; i += 1024) {
        const int excl = (i == 0) ? 0 : s[i - 1];
        cell_start[i] = excl;
        cursor[i]     = excl;     // scatter cursor
    }
    if (t == 0) cell_start[ncells] = s[ncells - 1];
}

__global__ void scatter_kernel(const float* __restrict__ xyz,
                               const int* __restrict__ xyz_cnt,
                               int* __restrict__ cursor,
                               float4* __restrict__ sorted,
                               int B, int Ntot) {
    const int p = blockIdx.x * blockDim.x + threadIdx.x;
    if (p >= Ntot) return;
    int b, boff; find_batch(xyz_cnt, B, p, &b, &boff);
    const float x = xyz[(size_t)p * 3 + 0];
    const float y = xyz[(size_t)p * 3 + 1];
    const float z = xyz[(size_t)p * 3 + 2];
    const int cell = b * GD3 + cell_of(x, y, z);
    const int slot = atomicAdd(&cursor[cell], 1);
    sorted[slot] = make_float4(x, y, z, __int_as_float(p - boff));
}

// ---------------- main: grid query + group ----------------

__global__ __launch_bounds__(256) void qgp_kernel(
    const float* __restrict__ xyz,        // (Ntot,3) original order (phase-2 gather)
    const int*   __restrict__ xyz_cnt,
    const float* __restrict__ nxyz,
    const float* __restrict__ nr,
    const int*   __restrict__ nxyz_cnt,
    const float* __restrict__ feat,       // (Ntot,C)
    const int*   __restrict__ cell_start, // (B*GD3+1)
    const float4* __restrict__ sorted,    // (Ntot) {x,y,z,local_idx_bits}
    float* __restrict__ out_feat,         // (Mtot, 3+C, NS)
    float* __restrict__ out_idx,          // (Mtot, NS) as float
    int B, int Mtot, int C)
{
    __shared__ int c_list[WPB][CAP];
    __shared__ int idx_buf[WPB][NS];

    const int wv   = threadIdx.x >> 6;
    const int lane = threadIdx.x & 63;
    const int q    = blockIdx.x * WPB + wv;
    if (q >= Mtot) return;

    int b, qoff; find_batch(nxyz_cnt, B, q, &b, &qoff);
    int xoff; { int acc = 0; xoff = 0;
        for (int i = 0; i < B; ++i) { int c = xyz_cnt[i]; if (i == b) xoff = acc; acc += c; } }
    const float* xb = xyz + (size_t)xoff * 3;

    const float qx = nxyz[(size_t)q * 3 + 0];
    const float qy = nxyz[(size_t)q * 3 + 1];
    const float qz = nxyz[(size_t)q * 3 + 2];
    const float r  = nr[q];
    const float r2 = __fmul_rn(r, r);

    // cell ranges (epsilon-widened; membership still decided by exact d2<r2)
    const float re = r + 1e-4f;
    const int cx0 = clampi((int)floorf(qx - re), 0, GD - 1);
    const int cx1 = clampi((int)floorf(qx + re), 0, GD - 1);
    const int cy0 = clampi((int)floorf(qy - re), 0, GD - 1);
    const int cy1 = clampi((int)floorf(qy + re), 0, GD - 1);
    const int cz0 = clampi((int)floorf(qz - re), 0, GD - 1);
    const int cz1 = clampi((int)floorf(qz + re), 0, GD - 1);
    const int cbase = b * GD3;

    const unsigned long long lane_mask = (1ull << lane) - 1ull;

    // ---- collect in-radius candidates (unordered) ----
    int n = 0;
    for (int cz = cz0; cz <= cz1; ++cz) {
        for (int cy = cy0; cy <= cy1; ++cy) {
            const int rb = cbase + (cz * GD + cy) * GD;
            const int s0 = cell_start[rb + cx0];
            const int s1 = cell_start[rb + cx1 + 1];
            for (int k0 = s0; k0 < s1; k0 += 64) {
                const int k = k0 + lane;
                bool ok = false; int ib = 0;
                if (k < s1) {
                    const float4 P = sorted[k];
                    ok = dist2_xla(qx, qy, qz, P.x, P.y, P.z) < r2;
                    ib = __float_as_int(P.w);
                }
                const unsigned long long m = __ballot(ok);
                if (ok) {
                    const int pos = n + __popcll(m & lane_mask);
                    if (pos < CAP) c_list[wv][pos] = ib;
                }
                n += __popcll(m);
            }
        }
    }
    if (n > CAP) n = CAP;
    __builtin_amdgcn_wave_barrier();

    // ---- select min(n,NS) smallest indices, ascending, into idx_buf ----
    int c0 = (lane       < n) ? c_list[wv][lane      ] : IMAX;
    int c1 = (lane +  64 < n) ? c_list[wv][lane +  64] : IMAX;
    int c2 = (lane + 128 < n) ? c_list[wv][lane + 128] : IMAX;
    int c3 = (lane + 192 < n) ? c_list[wv][lane + 192] : IMAX;
    const int filled = n < NS ? n : NS;
    for (int i = 0; i < filled; ++i) {
        const int mv = min(min(c0, c1), min(c2, c3));
        int w = mv;
#pragma unroll
        for (int d = 1; d < 64; d <<= 1) w = min(w, __shfl_xor(w, d));
        if (lane == i) idx_buf[wv][i] = w;
        const unsigned long long mm = __ballot(mv == w);
        const int first = __ffsll((unsigned long long)mm) - 1;
        if (lane == first) {
            if      (c0 == w) c0 = IMAX;
            else if (c1 == w) c1 = IMAX;
            else if (c2 == w) c2 = IMAX;
            else              c3 = IMAX;
        }
    }
    __builtin_amdgcn_wave_barrier();

    // ---- phase 2: gather + write ----
    const bool empty = (n == 0);
    const int cnt32  = filled;
    const int s = lane & 31;
    const int h = lane >> 5;

    int sidx = 0;
    if (!empty) sidx = idx_buf[wv][(s < cnt32) ? s : 0];

    const size_t ob = (size_t)q * (size_t)(3 + C) * NS;

    if (h == 0) {
        out_idx[(size_t)q * NS + s] = (float)sidx;
        float px = 0.f, py = 0.f, pz = 0.f;
        if (!empty) {
            px = __fsub_rn(xb[(size_t)sidx * 3 + 0], qx);
            py = __fsub_rn(xb[(size_t)sidx * 3 + 1], qy);
            pz = __fsub_rn(xb[(size_t)sidx * 3 + 2], qz);
        }
        out_feat[ob + 0 * NS + s] = px;
        out_feat[ob + 1 * NS + s] = py;
        out_feat[ob + 2 * NS + s] = pz;
    }

    const float* frow = feat + (size_t)(xoff + sidx) * C;
    if (C == 64) {
        const float4* frow4 = reinterpret_cast<const float4*>(frow);
#pragma unroll
        for (int j = 0; j < 8; ++j) {
            float4 f;
            if (empty) { f.x = f.y = f.z = f.w = 0.f; }
            else       { f = frow4[h * 8 + j]; }
            const int cb = 3 + h * 32 + j * 4;
            out_feat[ob + (size_t)(cb + 0) * NS + s] = f.x;
            out_feat[ob + (size_t)(cb + 1) * NS + s] = f.y;
            out_feat[ob + (size_t)(cb + 2) * NS + s] = f.z;
            out_feat[ob + (size_t)(cb + 3) * NS + s] = f.w;
        }
    } else {
        for (int c = h; c < C; c += 2) {
            out_feat[ob + (size_t)(3 + c) * NS + s] = empty ? 0.f : frow[c];
        }
    }
}

// ---------------- fallback: proven full-scan kernel ----------------

__global__ __launch_bounds__(256) void qgp_scan_kernel(
    const float* __restrict__ xyz, const int* __restrict__ xyz_cnt,
    const float* __restrict__ nxyz, const float* __restrict__ nr,
    const int* __restrict__ nxyz_cnt, const float* __restrict__ feat,
    float* __restrict__ out_feat, float* __restrict__ out_idx,
    int B, int Mtot, int C)
{
    __shared__ int idx_buf[WPB][NS];
    const int wv = threadIdx.x >> 6, lane = threadIdx.x & 63;
    const int q = blockIdx.x * WPB + wv;
    if (q >= Mtot) return;
    int b, qoff; find_batch(nxyz_cnt, B, q, &b, &qoff);
    int xoff = 0, npts = 0; { int acc = 0;
        for (int i = 0; i < B; ++i) { int c = xyz_cnt[i]; if (i == b) { xoff = acc; npts = c; } acc += c; } }
    const float* xb = xyz + (size_t)xoff * 3;
    const float qx = nxyz[(size_t)q*3], qy = nxyz[(size_t)q*3+1], qz = nxyz[(size_t)q*3+2];
    const float r = nr[q], r2 = __fmul_rn(r, r);
    const unsigned long long lane_mask = (1ull << lane) - 1ull;
    int cnt = 0;
    for (int base = 0; base < npts && cnt < NS; base += 64) {
        const int k = base + lane;
        bool ok = false;
        if (k < npts)
            ok = dist2_xla(qx,qy,qz, xb[(size_t)k*3], xb[(size_t)k*3+1], xb[(size_t)k*3+2]) < r2;
        const unsigned long long m = __ballot(ok);
        if (ok) { const int pos = cnt + __popcll(m & lane_mask); if (pos < NS) idx_buf[wv][pos] = k; }
        cnt += __popcll(m);
    }
    __builtin_amdgcn_wave_barrier();
    const bool empty = (cnt == 0);
    const int cnt32 = cnt < NS ? cnt : NS;
    const int s = lane & 31, h = lane >> 5;
    int sidx = 0;
    if (!empty) sidx = idx_buf[wv][(s < cnt32) ? s : 0];
    const size_t ob = (size_t)q * (size_t)(3 + C) * NS;
    if (h == 0) {
        out_idx[(size_t)q * NS + s] = (float)sidx;
        float px=0.f, py=0.f, pz=0.f;
        if (!empty) {
            px = __fsub_rn(xb[(size_t)sidx*3+0], qx);
            py = __fsub_rn(xb[(size_t)sidx*3+1], qy);
            pz = __fsub_rn(xb[(size_t)sidx*3+2], qz);
        }
        out_feat[ob + 0*NS + s] = px; out_feat[ob + 1*NS + s] = py; out_feat[ob + 2*NS + s] = pz;
    }
    const float* frow = feat + (size_t)(xoff + sidx) * C;
    for (int c = h; c < C; c += 2)
        out_feat[ob + (size_t)(3 + c) * NS + s] = empty ? 0.f : frow[c];
}

extern "C" void kernel_launch(void* const* d_in, const int* in_sizes, int n_in,
                              void* d_out, int out_size, void* d_ws, size_t ws_size,
                              hipStream_t stream) {
    const float* xyz      = (const float*)d_in[0];
    const int*   xyz_cnt  = (const int*)d_in[1];
    const float* nxyz     = (const float*)d_in[2];
    const float* nr       = (const float*)d_in[3];
    const int*   nxyz_cnt = (const int*)d_in[4];
    const float* feat     = (const float*)d_in[5];

    const int B    = in_sizes[1];
    const int Ntot = in_sizes[0] / 3;
    const int Mtot = in_sizes[2] / 3;
    const int C    = in_sizes[5] / Ntot;

    float* out_feat = (float*)d_out;
    float* out_idx  = out_feat + (size_t)Mtot * (size_t)(3 + C) * NS;

    const int ncells = B * GD3;
    const size_t off_start  = 0;
    const size_t off_cursor = ((size_t)(ncells + 1) * 4 + 255) & ~(size_t)255;
    const size_t off_sorted = (off_cursor + (size_t)ncells * 4 + 255) & ~(size_t)255;
    const size_t need       = off_sorted + (size_t)Ntot * sizeof(float4);

    const bool grid_ok = (ws_size >= need) && (ncells + 1 <= 2048);

    if (grid_ok) {
        char* ws = (char*)d_ws;
        int*    cell_start = (int*)(ws + off_start);
        int*    cursor     = (int*)(ws + off_cursor);
        float4* sorted     = (float4*)(ws + off_sorted);

        hipMemsetAsync(cursor, 0, (size_t)ncells * 4, stream);
        count_kernel<<<(Ntot + 255) / 256, 256, 0, stream>>>(xyz, xyz_cnt, cursor, B, Ntot);
        prefix_kernel<<<1, 1024, 0, stream>>>(cursor, cell_start, ncells);
        scatter_kernel<<<(Ntot + 255) / 256, 256, 0, stream>>>(xyz, xyz_cnt, cursor, sorted, B, Ntot);
        qgp_kernel<<<(Mtot + WPB - 1) / WPB, 256, 0, stream>>>(
            xyz, xyz_cnt, nxyz, nr, nxyz_cnt, feat, cell_start, sorted,
            out_feat, out_idx, B, Mtot, C);
    } else {
        qgp_scan_kernel<<<(Mtot + WPB - 1) / WPB, 256, 0, stream>>>(
            xyz, xyz_cnt, nxyz, nr, nxyz_cnt, feat, out_feat, out_idx, B, Mtot, C);
    }
}

// Round 8
// 132.954 us; speedup vs baseline: 1.4215x; 1.0175x over previous
//
#include <hip/hip_runtime.h>
#include <hip/hip_bf16.h>

#define NS   32          // nsample (fixed by setup_inputs)
#define WPB  4           // waves per block (block = 256 threads)
#define GD   10          // grid cells per axis; CELL = 1.0 over [0,10]^3 box
#define GD3  (GD*GD*GD)
#define BMW  1024        // bitmap words per wave: 32768 bits >= npts (host-guarded)

__device__ __forceinline__ int clampi(int v, int lo, int hi) {
    return v < lo ? lo : (v > hi ? hi : v);
}

__device__ __forceinline__ int cell_of(float x, float y, float z) {
    const int cx = clampi((int)floorf(x), 0, GD - 1);
    const int cy = clampi((int)floorf(y), 0, GD - 1);
    const int cz = clampi((int)floorf(z), 0, GD - 1);
    return (cz * GD + cy) * GD + cx;   // x fastest -> x-rows contiguous
}

__device__ __forceinline__ float dist2_xla(float qx, float qy, float qz,
                                           float x, float y, float z) {
    // match XLA exactly: sub, mul, left-assoc add, NO fma contraction
    const float dx = __fsub_rn(qx, x);
    const float dy = __fsub_rn(qy, y);
    const float dz = __fsub_rn(qz, z);
    return __fadd_rn(__fadd_rn(__fmul_rn(dx, dx), __fmul_rn(dy, dy)),
                     __fmul_rn(dz, dz));
}

__device__ __forceinline__ void find_batch(const int* cnts, int B, int p,
                                           int* b_out, int* off_out) {
    int b = 0, off = 0, acc = 0;
    for (int i = 0; i < B; ++i) {
        int c = cnts[i];
        if (p >= acc) { b = i; off = acc; }
        acc += c;
    }
    *b_out = b; *off_out = off;
}

// ---------------- grid build ----------------

__global__ void count_kernel(const float* __restrict__ xyz,
                             const int* __restrict__ xyz_cnt,
                             int* __restrict__ cnt, int B, int Ntot) {
    const int p = blockIdx.x * blockDim.x + threadIdx.x;
    if (p >= Ntot) return;
    int b, boff; find_batch(xyz_cnt, B, p, &b, &boff);
    const float x = xyz[(size_t)p * 3 + 0];
    const float y = xyz[(size_t)p * 3 + 1];
    const float z = xyz[(size_t)p * 3 + 2];
    atomicAdd(&cnt[b * GD3 + cell_of(x, y, z)], 1);
}

// single block; requires ncells+1 <= 2048
__global__ __launch_bounds__(1024) void prefix_kernel(int* __restrict__ cursor,     // in: counts, out: excl prefix
                                                      int* __restrict__ cell_start, // out: (ncells+1)
                                                      int ncells) {
    __shared__ int s[2048];
    const int t = threadIdx.x;
    for (int i = t; i < 2048; i += 1024) s[i] = (i < ncells) ? cursor[i] : 0;
    __syncthreads();
    for (int off = 1; off < 2048; off <<= 1) {
        const int v0 = s[t];
        const int a0 = (t >= off) ? s[t - off] : 0;
        const int v1 = s[t + 1024];
        const int a1 = s[t + 1024 - off];
        __syncthreads();
        s[t] = v0 + a0;
        s[t + 1024] = v1 + a1;
        __syncthreads();
    }
    for (int i = t; i < ncells; i += 1024) {
        const int excl = (i == 0) ? 0 : s[i - 1];
        cell_start[i] = excl;
        cursor[i]     = excl;     // scatter cursor
    }
    if (t == 0) cell_start[ncells] = s[ncells - 1];
}

__global__ void scatter_kernel(const float* __restrict__ xyz,
                               const int* __restrict__ xyz_cnt,
                               int* __restrict__ cursor,
                               float4* __restrict__ sorted,
                               int B, int Ntot) {
    const int p = blockIdx.x * blockDim.x + threadIdx.x;
    if (p >= Ntot) return;
    int b, boff; find_batch(xyz_cnt, B, p, &b, &boff);
    const float x = xyz[(size_t)p * 3 + 0];
    const float y = xyz[(size_t)p * 3 + 1];
    const float z = xyz[(size_t)p * 3 + 2];
    const int cell = b * GD3 + cell_of(x, y, z);
    const int slot = atomicAdd(&cursor[cell], 1);
    sorted[slot] = make_float4(x, y, z, __int_as_float(p - boff));
}

// ---------------- main: grid query + bitmap select + group ----------------
// Per-wave index bitmap replaces list+argmin-extraction: collection atomicOrs
// bit(ib); emit pass scans words in index order (16 words/lane, permuted
// conflict-free layout), popcount + wave exclusive scan gives each lane its
// output offsets; first NS set bits (ascending index == reference top_k(-key))
// land in idx_buf.
__global__ __launch_bounds__(256) void qgp_kernel(
    const float* __restrict__ xyz,        // (Ntot,3) original order (phase-2 gather)
    const int*   __restrict__ xyz_cnt,
    const float* __restrict__ nxyz,
    const float* __restrict__ nr,
    const int*   __restrict__ nxyz_cnt,
    const float* __restrict__ feat,       // (Ntot,C)
    const int*   __restrict__ cell_start, // (B*GD3+1)
    const float4* __restrict__ sorted,    // (Ntot) {x,y,z,local_idx_bits}
    float* __restrict__ out_feat,         // (Mtot, 3+C, NS)
    float* __restrict__ out_idx,          // (Mtot, NS) as float
    int B, int Mtot, int C)
{
    __shared__ unsigned bm[WPB][BMW];     // 4 KiB per wave
    __shared__ int idx_buf[WPB][NS];

    const int wv   = threadIdx.x >> 6;
    const int lane = threadIdx.x & 63;
    const int q    = blockIdx.x * WPB + wv;
    if (q >= Mtot) return;

    // clear this wave's bitmap (strided: offset lane + 64*t, conflict-free)
#pragma unroll
    for (int t = 0; t < BMW / 64; ++t) bm[wv][lane + 64 * t] = 0u;

    int b, qoff; find_batch(nxyz_cnt, B, q, &b, &qoff);
    int xoff; { int acc = 0; xoff = 0;
        for (int i = 0; i < B; ++i) { int c = xyz_cnt[i]; if (i == b) xoff = acc; acc += c; } }
    const float* xb = xyz + (size_t)xoff * 3;

    const float qx = nxyz[(size_t)q * 3 + 0];
    const float qy = nxyz[(size_t)q * 3 + 1];
    const float qz = nxyz[(size_t)q * 3 + 2];
    const float r  = nr[q];
    const float r2 = __fmul_rn(r, r);

    // cell ranges (epsilon-widened; membership still decided by exact d2<r2)
    const float re = r + 1e-4f;
    const int cx0 = clampi((int)floorf(qx - re), 0, GD - 1);
    const int cx1 = clampi((int)floorf(qx + re), 0, GD - 1);
    const int cy0 = clampi((int)floorf(qy - re), 0, GD - 1);
    const int cy1 = clampi((int)floorf(qy + re), 0, GD - 1);
    const int cz0 = clampi((int)floorf(qz - re), 0, GD - 1);
    const int cz1 = clampi((int)floorf(qz + re), 0, GD - 1);
    const int cbase = b * GD3;

    __builtin_amdgcn_wave_barrier();      // clears complete before atomics

    // ---- collect: set bit(ib) for every in-radius candidate ----
    for (int cz = cz0; cz <= cz1; ++cz) {
        for (int cy = cy0; cy <= cy1; ++cy) {
            const int rb = cbase + (cz * GD + cy) * GD;
            const int s0 = cell_start[rb + cx0];
            const int s1 = cell_start[rb + cx1 + 1];
            for (int k0 = s0; k0 < s1; k0 += 64) {
                const int k = k0 + lane;
                if (k < s1) {
                    const float4 P = sorted[k];
                    if (dist2_xla(qx, qy, qz, P.x, P.y, P.z) < r2) {
                        const int ib = __float_as_int(P.w);
                        const int wi = ib >> 5;
                        // permuted layout: word wi at offset (wi&15)*64 + (wi>>4)
                        atomicOr(&bm[wv][((wi & 15) << 6) + (wi >> 4)],
                                 1u << (ib & 31));
                    }
                }
            }
        }
    }
    __builtin_amdgcn_wave_barrier();

    // ---- emit: single-pass ordered scan of the bitmap ----
    // lane owns words wi = lane*16 + j (j=0..15) -> indices [lane*512, lane*512+512)
    unsigned words[16];
    int mytot = 0;
#pragma unroll
    for (int j = 0; j < 16; ++j) {
        words[j] = bm[wv][(j << 6) + lane];   // perm: (wi&15)=j, (wi>>4)=lane
        mytot += __popc(words[j]);
    }
    int incl = mytot;
#pragma unroll
    for (int d = 1; d < 64; d <<= 1) {
        const int v = __shfl_up(incl, d);
        if (lane >= d) incl += v;
    }
    const int total = __shfl(incl, 63);
    int pos = incl - mytot;                   // exclusive prefix
    if (pos < NS) {
        for (int j = 0; j < 16 && pos < NS; ++j) {
            unsigned w = words[j];
            while (w && pos < NS) {
                const int bit = __ffs(w) - 1;
                idx_buf[wv][pos] = (lane << 9) + (j << 5) + bit;
                ++pos;
                w &= w - 1;
            }
        }
    }
    __builtin_amdgcn_wave_barrier();

    // ---- phase 2: gather + write ----
    const bool empty = (total == 0);
    const int cnt32  = total < NS ? total : NS;
    const int s = lane & 31;
    const int h = lane >> 5;

    int sidx = 0;
    if (!empty) sidx = idx_buf[wv][(s < cnt32) ? s : 0];

    const size_t ob = (size_t)q * (size_t)(3 + C) * NS;

    if (h == 0) {
        out_idx[(size_t)q * NS + s] = (float)sidx;
        float px = 0.f, py = 0.f, pz = 0.f;
        if (!empty) {
            px = __fsub_rn(xb[(size_t)sidx * 3 + 0], qx);
            py = __fsub_rn(xb[(size_t)sidx * 3 + 1], qy);
            pz = __fsub_rn(xb[(size_t)sidx * 3 + 2], qz);
        }
        out_feat[ob + 0 * NS + s] = px;
        out_feat[ob + 1 * NS + s] = py;
        out_feat[ob + 2 * NS + s] = pz;
    }

    const float* frow = feat + (size_t)(xoff + sidx) * C;
    if (C == 64) {
        const float4* frow4 = reinterpret_cast<const float4*>(frow);
#pragma unroll
        for (int j = 0; j < 8; ++j) {
            float4 f;
            if (empty) { f.x = f.y = f.z = f.w = 0.f; }
            else       { f = frow4[h * 8 + j]; }
            const int cb = 3 + h * 32 + j * 4;
            out_feat[ob + (size_t)(cb + 0) * NS + s] = f.x;
            out_feat[ob + (size_t)(cb + 1) * NS + s] = f.y;
            out_feat[ob + (size_t)(cb + 2) * NS + s] = f.z;
            out_feat[ob + (size_t)(cb + 3) * NS + s] = f.w;
        }
    } else {
        for (int c = h; c < C; c += 2) {
            out_feat[ob + (size_t)(3 + c) * NS + s] = empty ? 0.f : frow[c];
        }
    }
}

// ---------------- fallback: proven full-scan kernel ----------------

__global__ __launch_bounds__(256) void qgp_scan_kernel(
    const float* __restrict__ xyz, const int* __restrict__ xyz_cnt,
    const float* __restrict__ nxyz, const float* __restrict__ nr,
    const int* __restrict__ nxyz_cnt, const float* __restrict__ feat,
    float* __restrict__ out_feat, float* __restrict__ out_idx,
    int B, int Mtot, int C)
{
    __shared__ int idx_buf[WPB][NS];
    const int wv = threadIdx.x >> 6, lane = threadIdx.x & 63;
    const int q = blockIdx.x * WPB + wv;
    if (q >= Mtot) return;
    int b, qoff; find_batch(nxyz_cnt, B, q, &b, &qoff);
    int xoff = 0, npts = 0; { int acc = 0;
        for (int i = 0; i < B; ++i) { int c = xyz_cnt[i]; if (i == b) { xoff = acc; npts = c; } acc += c; } }
    const float* xb = xyz + (size_t)xoff * 3;
    const float qx = nxyz[(size_t)q*3], qy = nxyz[(size_t)q*3+1], qz = nxyz[(size_t)q*3+2];
    const float r = nr[q], r2 = __fmul_rn(r, r);
    const unsigned long long lane_mask = (1ull << lane) - 1ull;
    int cnt = 0;
    for (int base = 0; base < npts && cnt < NS; base += 64) {
        const int k = base + lane;
        bool ok = false;
        if (k < npts)
            ok = dist2_xla(qx,qy,qz, xb[(size_t)k*3], xb[(size_t)k*3+1], xb[(size_t)k*3+2]) < r2;
        const unsigned long long m = __ballot(ok);
        if (ok) { const int pos = cnt + __popcll(m & lane_mask); if (pos < NS) idx_buf[wv][pos] = k; }
        cnt += __popcll(m);
    }
    __builtin_amdgcn_wave_barrier();
    const bool empty = (cnt == 0);
    const int cnt32 = cnt < NS ? cnt : NS;
    const int s = lane & 31, h = lane >> 5;
    int sidx = 0;
    if (!empty) sidx = idx_buf[wv][(s < cnt32) ? s : 0];
    const size_t ob = (size_t)q * (size_t)(3 + C) * NS;
    if (h == 0) {
        out_idx[(size_t)q * NS + s] = (float)sidx;
        float px=0.f, py=0.f, pz=0.f;
        if (!empty) {
            px = __fsub_rn(xb[(size_t)sidx*3+0], qx);
            py = __fsub_rn(xb[(size_t)sidx*3+1], qy);
            pz = __fsub_rn(xb[(size_t)sidx*3+2], qz);
        }
        out_feat[ob + 0*NS + s] = px; out_feat[ob + 1*NS + s] = py; out_feat[ob + 2*NS + s] = pz;
    }
    const float* frow = feat + (size_t)(xoff + sidx) * C;
    for (int c = h; c < C; c += 2)
        out_feat[ob + (size_t)(3 + c) * NS + s] = empty ? 0.f : frow[c];
}

extern "C" void kernel_launch(void* const* d_in, const int* in_sizes, int n_in,
                              void* d_out, int out_size, void* d_ws, size_t ws_size,
                              hipStream_t stream) {
    const float* xyz      = (const float*)d_in[0];
    const int*   xyz_cnt  = (const int*)d_in[1];
    const float* nxyz     = (const float*)d_in[2];
    const float* nr       = (const float*)d_in[3];
    const int*   nxyz_cnt = (const int*)d_in[4];
    const float* feat     = (const float*)d_in[5];

    const int B    = in_sizes[1];
    const int Ntot = in_sizes[0] / 3;
    const int Mtot = in_sizes[2] / 3;
    const int C    = in_sizes[5] / Ntot;

    float* out_feat = (float*)d_out;
    float* out_idx  = out_feat + (size_t)Mtot * (size_t)(3 + C) * NS;

    const int ncells = B * GD3;
    const size_t off_start  = 0;
    const size_t off_cursor = ((size_t)(ncells + 1) * 4 + 255) & ~(size_t)255;
    const size_t off_sorted = (off_cursor + (size_t)ncells * 4 + 255) & ~(size_t)255;
    const size_t need       = off_sorted + (size_t)Ntot * sizeof(float4);

    // bitmap covers per-batch npts <= Ntot <= BMW*32
    const bool grid_ok = (ws_size >= need) && (ncells + 1 <= 2048) &&
                         (Ntot <= BMW * 32);

    if (grid_ok) {
        char* ws = (char*)d_ws;
        int*    cell_start = (int*)(ws + off_start);
        int*    cursor     = (int*)(ws + off_cursor);
        float4* sorted     = (float4*)(ws + off_sorted);

        hipMemsetAsync(cursor, 0, (size_t)ncells * 4, stream);
        count_kernel<<<(Ntot + 255) / 256, 256, 0, stream>>>(xyz, xyz_cnt, cursor, B, Ntot);
        prefix_kernel<<<1, 1024, 0, stream>>>(cursor, cell_start, ncells);
        scatter_kernel<<<(Ntot + 255) / 256, 256, 0, stream>>>(xyz, xyz_cnt, cursor, sorted, B, Ntot);
        qgp_kernel<<<(Mtot + WPB - 1) / WPB, 256, 0, stream>>>(
            xyz, xyz_cnt, nxyz, nr, nxyz_cnt, feat, cell_start, sorted,
            out_feat, out_idx, B, Mtot, C);
    } else {
        qgp_scan_kernel<<<(Mtot + WPB - 1) / WPB, 256, 0, stream>>>(
            xyz, xyz_cnt, nxyz, nr, nxyz_cnt, feat, out_feat, out_idx, B, Mtot, C);
    }
}